// Round 1
// baseline (2352.302 us; speedup 1.0000x reference)
//
#include <hip/hip_runtime.h>
#include <hip/hip_bf16.h>

// ---------------------------------------------------------------------------
// EncoderGAE: 8-layer GCN encoder on MI355X.
// Structure per call:
//   1. deg/dinv + per-edge norm (gcn_norm with self-loops handled analytically)
//   2. CSR-by-dst build (histogram -> single-block scan -> bucket fill)
//   3. layer 0: X = h[N,6] @ W1
//   4. per layer: [GEMM] -> gather-aggregate (self-loop + bias fused)
//                 -> BN stats -> BN apply + leakyReLU (layers 0..6)
// Ping-pong activations between ws buffer A and d_out; layer 7 lands in d_out.
// ---------------------------------------------------------------------------

#define NN 50000
#define NE 800000
#define DD 256

__global__ void deg_init_kernel(float* deg) {
    int i = blockIdx.x * 256 + threadIdx.x;
    if (i < NN) deg[i] = 1.0f;  // self-loop weight 1 contributes to own deg
}

__global__ void deg_scatter_kernel(const int* __restrict__ dst,
                                   const float* __restrict__ ew,
                                   float* deg) {
    int e = blockIdx.x * 256 + threadIdx.x;
    if (e < NE) unsafeAtomicAdd(&deg[dst[e]], ew[e]);
}

__global__ void dinv_kernel(float* deg) {
    int i = blockIdx.x * 256 + threadIdx.x;
    if (i < NN) {
        float d = deg[i];
        deg[i] = (d > 0.0f) ? rsqrtf(fmaxf(d, 1e-30f)) : 0.0f;
    }
}

// norm[e] = dinv[src]*ew*dinv[dst]; also histogram counts per dst.
__global__ void norm_cnt_kernel(const int* __restrict__ src,
                                const int* __restrict__ dst,
                                const float* __restrict__ ew,
                                const float* __restrict__ dinv,
                                float* __restrict__ norm,
                                int* __restrict__ cnt) {
    int e = blockIdx.x * 256 + threadIdx.x;
    if (e < NE) {
        int s = src[e], d = dst[e];
        norm[e] = dinv[s] * ew[e] * dinv[d];
        atomicAdd(&cnt[d], 1);
    }
}

// Single-block exclusive scan of cnt[0..n) -> rowptr, rowptr[n] = total.
__global__ void scan_kernel(const int* __restrict__ cnt, int* __restrict__ rowptr, int n) {
    __shared__ int wsum[16];
    __shared__ int carry_s;
    int tid = threadIdx.x;
    int lane = tid & 63;
    int wid = tid >> 6;
    if (tid == 0) carry_s = 0;
    __syncthreads();
    for (int base = 0; base < n; base += 1024) {
        int i = base + tid;
        int v = (i < n) ? cnt[i] : 0;
        int x = v;
        #pragma unroll
        for (int o = 1; o < 64; o <<= 1) {
            int y = __shfl_up(x, o, 64);
            if (lane >= o) x += y;
        }
        if (lane == 63) wsum[wid] = x;
        __syncthreads();
        if (wid == 0) {
            int w = (lane < 16) ? wsum[lane] : 0;
            #pragma unroll
            for (int o = 1; o < 16; o <<= 1) {
                int y = __shfl_up(w, o, 64);
                if (lane >= o) w += y;
            }
            if (lane < 16) wsum[lane] = w;
        }
        __syncthreads();
        int wexcl = (wid > 0) ? wsum[wid - 1] : 0;
        int incl = x + wexcl;
        int c = carry_s;
        if (i < n) rowptr[i] = c + incl - v;
        __syncthreads();
        if (tid == 1023) carry_s = c + wsum[15];
        __syncthreads();
    }
    if (tid == 0) rowptr[n] = carry_s;
}

// Scatter edges into dst-buckets (cursor = cnt, zeroed beforehand).
__global__ void fill_kernel(const int* __restrict__ src,
                            const int* __restrict__ dst,
                            const float* __restrict__ norm,
                            const int* __restrict__ rowptr,
                            int* __restrict__ cursor,
                            int* __restrict__ srcp,
                            float* __restrict__ normp) {
    int e = blockIdx.x * 256 + threadIdx.x;
    if (e < NE) {
        int d = dst[e];
        int p = rowptr[d] + atomicAdd(&cursor[d], 1);
        srcp[p] = src[e];
        normp[p] = norm[e];
    }
}

// Layer-0 GEMM: X[N,256] = h[N,6] @ W1[6,256]. One block per node.
__global__ void gemm0_kernel(const float* __restrict__ h,
                             const float* __restrict__ W1,
                             float* __restrict__ X) {
    __shared__ float hs[6];
    int i = blockIdx.x;
    int f = threadIdx.x;
    if (f < 6) hs[f] = h[i * 6 + f];
    __syncthreads();
    float s = 0.0f;
    #pragma unroll
    for (int k = 0; k < 6; ++k) s = fmaf(hs[k], W1[k * 256 + f], s);
    X[(size_t)i * 256 + f] = s;
}

// fp32 tiled GEMM: C[M,256] = A[M,256] @ B[256,256], 64x64 tile, 4x4/thread.
__launch_bounds__(256)
__global__ void gemm_f32_kernel(const float* __restrict__ A,
                                const float* __restrict__ B,
                                float* __restrict__ C, int M) {
    __shared__ __align__(16) float As[16][64];
    __shared__ __align__(16) float Bs[16][64];
    int tid = threadIdx.x;
    int row0 = blockIdx.y * 64;
    int col0 = blockIdx.x * 64;
    int arow = tid >> 2;            // 0..63
    int acol = (tid & 3) << 2;      // 0,4,8,12
    int brow = tid >> 4;            // 0..15
    int bcol = (tid & 15) << 2;     // 0..60
    int tx = tid & 15, ty = tid >> 4;
    float acc[4][4] = {};
    for (int k0 = 0; k0 < 256; k0 += 16) {
        float4 av = make_float4(0.f, 0.f, 0.f, 0.f);
        int gr = row0 + arow;
        if (gr < M) av = *(const float4*)(A + (size_t)gr * 256 + k0 + acol);
        As[acol + 0][arow] = av.x;
        As[acol + 1][arow] = av.y;
        As[acol + 2][arow] = av.z;
        As[acol + 3][arow] = av.w;
        float4 bv = *(const float4*)(B + (size_t)(k0 + brow) * 256 + col0 + bcol);
        *(float4*)&Bs[brow][bcol] = bv;
        __syncthreads();
        #pragma unroll
        for (int k = 0; k < 16; ++k) {
            float4 a = *(const float4*)&As[k][ty << 2];
            float4 b = *(const float4*)&Bs[k][tx << 2];
            acc[0][0] = fmaf(a.x, b.x, acc[0][0]);
            acc[0][1] = fmaf(a.x, b.y, acc[0][1]);
            acc[0][2] = fmaf(a.x, b.z, acc[0][2]);
            acc[0][3] = fmaf(a.x, b.w, acc[0][3]);
            acc[1][0] = fmaf(a.y, b.x, acc[1][0]);
            acc[1][1] = fmaf(a.y, b.y, acc[1][1]);
            acc[1][2] = fmaf(a.y, b.z, acc[1][2]);
            acc[1][3] = fmaf(a.y, b.w, acc[1][3]);
            acc[2][0] = fmaf(a.z, b.x, acc[2][0]);
            acc[2][1] = fmaf(a.z, b.y, acc[2][1]);
            acc[2][2] = fmaf(a.z, b.z, acc[2][2]);
            acc[2][3] = fmaf(a.z, b.w, acc[2][3]);
            acc[3][0] = fmaf(a.w, b.x, acc[3][0]);
            acc[3][1] = fmaf(a.w, b.y, acc[3][1]);
            acc[3][2] = fmaf(a.w, b.z, acc[3][2]);
            acc[3][3] = fmaf(a.w, b.w, acc[3][3]);
        }
        __syncthreads();
    }
    #pragma unroll
    for (int i = 0; i < 4; ++i) {
        int gr = row0 + (ty << 2) + i;
        if (gr < M) {
            float4 o = make_float4(acc[i][0], acc[i][1], acc[i][2], acc[i][3]);
            *(float4*)(C + (size_t)gr * 256 + col0 + (tx << 2)) = o;
        }
    }
}

// Gather aggregation: one wave per dst node; self-loop + bias fused.
__global__ void agg_kernel(const float* __restrict__ X,
                           float* __restrict__ Y,
                           const int* __restrict__ rowptr,
                           const int* __restrict__ srcp,
                           const float* __restrict__ normp,
                           const float* __restrict__ dinv,
                           const float* __restrict__ bias) {
    int node = (blockIdx.x << 2) + (threadIdx.x >> 6);
    if (node >= NN) return;
    int lane = threadIdx.x & 63;
    const float4* X4 = (const float4*)X;
    float di = dinv[node];
    float w0 = di * di;
    float4 v = X4[(size_t)node * 64 + lane];
    float4 bb = ((const float4*)bias)[lane];
    float ax = fmaf(w0, v.x, bb.x);
    float ay = fmaf(w0, v.y, bb.y);
    float az = fmaf(w0, v.z, bb.z);
    float aw = fmaf(w0, v.w, bb.w);
    int j = rowptr[node], jend = rowptr[node + 1];
    for (; j < jend; ++j) {
        int s = srcp[j];
        float w = normp[j];
        float4 u = X4[(size_t)s * 64 + lane];
        ax = fmaf(w, u.x, ax);
        ay = fmaf(w, u.y, ay);
        az = fmaf(w, u.z, az);
        aw = fmaf(w, u.w, aw);
    }
    ((float4*)Y)[(size_t)node * 64 + lane] = make_float4(ax, ay, az, aw);
}

// BN stats: per-column sum and sumsq via block partials + atomics.
__global__ void bn_stats_kernel(const float* __restrict__ Y, float* __restrict__ stats) {
    int col = threadIdx.x;
    int r0 = blockIdx.x * 128;
    int rend = min(r0 + 128, NN);
    float s = 0.f, ss = 0.f;
    for (int r = r0; r < rend; ++r) {
        float v = Y[(size_t)r * 256 + col];
        s += v;
        ss = fmaf(v, v, ss);
    }
    unsafeAtomicAdd(&stats[col], s);
    unsafeAtomicAdd(&stats[256 + col], ss);
}

// BN apply + leakyReLU, in place.
__global__ void bn_apply_kernel(float* __restrict__ Y,
                                const float* __restrict__ stats,
                                const float* __restrict__ g,
                                const float* __restrict__ be) {
    int idx = blockIdx.x * 256 + threadIdx.x;  // over NN*64 float4s
    if (idx >= NN * 64) return;
    int c4 = idx & 63;
    float4 v = ((const float4*)Y)[idx];
    float4 s = ((const float4*)stats)[c4];
    float4 ss = ((const float4*)(stats + 256))[c4];
    float4 gg = ((const float4*)g)[c4];
    float4 bb = ((const float4*)be)[c4];
    const float invN = 1.0f / (float)NN;
    float m, var, sc, o;
    m = s.x * invN; var = fmaf(-m, m, ss.x * invN); sc = rsqrtf(var + 1e-5f) * gg.x;
    o = fmaf(v.x - m, sc, bb.x); v.x = (o >= 0.f) ? o : 0.01f * o;
    m = s.y * invN; var = fmaf(-m, m, ss.y * invN); sc = rsqrtf(var + 1e-5f) * gg.y;
    o = fmaf(v.y - m, sc, bb.y); v.y = (o >= 0.f) ? o : 0.01f * o;
    m = s.z * invN; var = fmaf(-m, m, ss.z * invN); sc = rsqrtf(var + 1e-5f) * gg.z;
    o = fmaf(v.z - m, sc, bb.z); v.z = (o >= 0.f) ? o : 0.01f * o;
    m = s.w * invN; var = fmaf(-m, m, ss.w * invN); sc = rsqrtf(var + 1e-5f) * gg.w;
    o = fmaf(v.w - m, sc, bb.w); v.w = (o >= 0.f) ? o : 0.01f * o;
    ((float4*)Y)[idx] = v;
}

extern "C" void kernel_launch(void* const* d_in, const int* in_sizes, int n_in,
                              void* d_out, int out_size, void* d_ws, size_t ws_size,
                              hipStream_t stream) {
    const float* h   = (const float*)d_in[0];
    const int*   ei  = (const int*)d_in[1];
    const float* ew  = (const float*)d_in[2];
    const float* W1  = (const float*)d_in[3];
    const float* b1  = (const float*)d_in[4];
    const float* g1  = (const float*)d_in[5];
    const float* be1 = (const float*)d_in[6];
    const float* Wm  = (const float*)d_in[7];
    const float* bm  = (const float*)d_in[8];
    const float* gm  = (const float*)d_in[9];
    const float* bem = (const float*)d_in[10];
    const float* Wl  = (const float*)d_in[11];
    const float* bl  = (const float*)d_in[12];

    const int* src = ei;
    const int* dst = ei + NE;

    // Workspace layout (256B aligned). Total ~113 MB.
    char* ws = (char*)d_ws;
    size_t off = 0;
    auto alloc = [&](size_t bytes) { size_t o = off; off = (off + bytes + 255) & ~(size_t)255; return o; };
    float* X      = (float*)(ws + alloc((size_t)NN * DD * 4));
    float* Abuf   = (float*)(ws + alloc((size_t)NN * DD * 4));
    float* norm   = (float*)(ws + alloc((size_t)NE * 4));
    float* dinv   = (float*)(ws + alloc((size_t)NN * 4));
    float* stats  = (float*)(ws + alloc(512 * 4));
    int*   rowptr = (int*)  (ws + alloc((size_t)(NN + 1) * 4));
    int*   cnt    = (int*)  (ws + alloc((size_t)NN * 4));
    int*   srcp   = (int*)  (ws + alloc((size_t)NE * 4));
    float* normp  = (float*)(ws + alloc((size_t)NE * 4));
    (void)ws_size;

    float* OUT = (float*)d_out;

    const int gN = (NN + 255) / 256;
    const int gE = (NE + 255) / 256;

    // --- gcn_norm + CSR build ---
    deg_init_kernel<<<gN, 256, 0, stream>>>(dinv);
    deg_scatter_kernel<<<gE, 256, 0, stream>>>(dst, ew, dinv);
    dinv_kernel<<<gN, 256, 0, stream>>>(dinv);
    hipMemsetAsync(cnt, 0, (size_t)NN * 4, stream);
    norm_cnt_kernel<<<gE, 256, 0, stream>>>(src, dst, ew, dinv, norm, cnt);
    scan_kernel<<<1, 1024, 0, stream>>>(cnt, rowptr, NN);
    hipMemsetAsync(cnt, 0, (size_t)NN * 4, stream);
    fill_kernel<<<gE, 256, 0, stream>>>(src, dst, norm, rowptr, cnt, srcp, normp);

    // --- layer 0 GEMM ---
    gemm0_kernel<<<NN, 256, 0, stream>>>(h, W1, X);

    // --- 8 layers ---
    for (int l = 0; l < 8; ++l) {
        const float* b_l = (l == 0) ? b1 : (l <= 6 ? bm + (l - 1) * 256 : bl);
        float* Y = (l & 1) ? OUT : Abuf;
        if (l >= 1) {
            const float* prev = (l & 1) ? Abuf : OUT;  // output of layer l-1
            const float* W = (l <= 6) ? Wm + (size_t)(l - 1) * DD * DD : Wl;
            dim3 grid(4, (NN + 63) / 64);
            gemm_f32_kernel<<<grid, 256, 0, stream>>>(prev, W, X, NN);
        }
        agg_kernel<<<(NN + 3) / 4, 256, 0, stream>>>(X, Y, rowptr, srcp, normp, dinv, b_l);
        if (l < 7) {
            const float* g_l  = (l == 0) ? g1 : gm + (l - 1) * 256;
            const float* be_l = (l == 0) ? be1 : bem + (l - 1) * 256;
            hipMemsetAsync(stats, 0, 512 * 4, stream);
            bn_stats_kernel<<<(NN + 127) / 128, 256, 0, stream>>>(Y, stats);
            bn_apply_kernel<<<(NN * 64 + 255) / 256, 256, 0, stream>>>(Y, stats, g_l, be_l);
        }
    }
}

// Round 2
// 1625.259 us; speedup vs baseline: 1.4473x; 1.4473x over previous
//
#include <hip/hip_runtime.h>
#include <hip/hip_bf16.h>

// ---------------------------------------------------------------------------
// EncoderGAE: 8-layer GCN encoder on MI355X.
// R2: bf16 activations (halves gather traffic) + MFMA bf16 GEMM.
//   - X (GEMM output, gather source): bf16 [N,256], 512B rows
//   - Y (aggregation output, BN input): fp32
//   - Act (BN output, GEMM input): bf16
//   - Weights pre-transposed to Bt[N][K] bf16 once per call.
// ---------------------------------------------------------------------------

#define NN 50000
#define NE 800000
#define DD 256

typedef __attribute__((ext_vector_type(8))) short short8;
typedef __attribute__((ext_vector_type(4))) float f32x4;

static __device__ __forceinline__ ushort f2bf(float f) {
    unsigned u = __float_as_uint(f);
    unsigned r = (u + 0x7fffu + ((u >> 16) & 1u)) >> 16;   // RNE
    return (ushort)r;
}
static __device__ __forceinline__ float bf_lo(unsigned x) {
    return __uint_as_float(x << 16);
}
static __device__ __forceinline__ float bf_hi(unsigned x) {
    return __uint_as_float(x & 0xffff0000u);
}

// ------------------------- gcn_norm + CSR build ----------------------------

__global__ void deg_init_kernel(float* deg) {
    int i = blockIdx.x * 256 + threadIdx.x;
    if (i < NN) deg[i] = 1.0f;  // self-loop weight 1
}

__global__ void deg_scatter_kernel(const int* __restrict__ dst,
                                   const float* __restrict__ ew,
                                   float* deg) {
    int e = blockIdx.x * 256 + threadIdx.x;
    if (e < NE) unsafeAtomicAdd(&deg[dst[e]], ew[e]);
}

__global__ void dinv_kernel(float* deg) {
    int i = blockIdx.x * 256 + threadIdx.x;
    if (i < NN) {
        float d = deg[i];
        deg[i] = (d > 0.0f) ? rsqrtf(fmaxf(d, 1e-30f)) : 0.0f;
    }
}

__global__ void norm_cnt_kernel(const int* __restrict__ src,
                                const int* __restrict__ dst,
                                const float* __restrict__ ew,
                                const float* __restrict__ dinv,
                                float* __restrict__ norm,
                                int* __restrict__ cnt) {
    int e = blockIdx.x * 256 + threadIdx.x;
    if (e < NE) {
        int s = src[e], d = dst[e];
        norm[e] = dinv[s] * ew[e] * dinv[d];
        atomicAdd(&cnt[d], 1);
    }
}

__global__ void scan_kernel(const int* __restrict__ cnt, int* __restrict__ rowptr, int n) {
    __shared__ int wsum[16];
    __shared__ int carry_s;
    int tid = threadIdx.x;
    int lane = tid & 63;
    int wid = tid >> 6;
    if (tid == 0) carry_s = 0;
    __syncthreads();
    for (int base = 0; base < n; base += 1024) {
        int i = base + tid;
        int v = (i < n) ? cnt[i] : 0;
        int x = v;
        #pragma unroll
        for (int o = 1; o < 64; o <<= 1) {
            int y = __shfl_up(x, o, 64);
            if (lane >= o) x += y;
        }
        if (lane == 63) wsum[wid] = x;
        __syncthreads();
        if (wid == 0) {
            int w = (lane < 16) ? wsum[lane] : 0;
            #pragma unroll
            for (int o = 1; o < 16; o <<= 1) {
                int y = __shfl_up(w, o, 64);
                if (lane >= o) w += y;
            }
            if (lane < 16) wsum[lane] = w;
        }
        __syncthreads();
        int wexcl = (wid > 0) ? wsum[wid - 1] : 0;
        int incl = x + wexcl;
        int c = carry_s;
        if (i < n) rowptr[i] = c + incl - v;
        __syncthreads();
        if (tid == 1023) carry_s = c + wsum[15];
        __syncthreads();
    }
    if (tid == 0) rowptr[n] = carry_s;
}

__global__ void fill_kernel(const int* __restrict__ src,
                            const int* __restrict__ dst,
                            const float* __restrict__ norm,
                            const int* __restrict__ rowptr,
                            int* __restrict__ cursor,
                            int* __restrict__ srcp,
                            float* __restrict__ normp) {
    int e = blockIdx.x * 256 + threadIdx.x;
    if (e < NE) {
        int d = dst[e];
        int p = rowptr[d] + atomicAdd(&cursor[d], 1);
        srcp[p] = src[e];
        normp[p] = norm[e];
    }
}

// ---------------------- weight transpose + bf16 cvt ------------------------
// Bt[l][n][k] = W_l[k][n], l=0..5 -> Wm[l], l=6 -> Wl.
__global__ void wcvt_kernel(const float* __restrict__ Wm,
                            const float* __restrict__ Wl,
                            ushort* __restrict__ Bt) {
    int idx = blockIdx.x * 256 + threadIdx.x;
    if (idx >= 7 * 65536) return;
    int l = idx >> 16;
    int nk = idx & 65535;
    int n = nk >> 8, k = nk & 255;
    const float* W = (l < 6) ? (Wm + (size_t)l * 65536) : Wl;
    Bt[idx] = f2bf(W[k * 256 + n]);
}

// Layer-0: X[N,256] = h[N,6] @ W1[6,256], fp32 math, bf16 output.
__global__ void gemm0_kernel(const float* __restrict__ h,
                             const float* __restrict__ W1,
                             ushort* __restrict__ Xb) {
    __shared__ float hs[6];
    int i = blockIdx.x;
    int f = threadIdx.x;
    if (f < 6) hs[f] = h[i * 6 + f];
    __syncthreads();
    float s = 0.0f;
    #pragma unroll
    for (int k = 0; k < 6; ++k) s = fmaf(hs[k], W1[k * 256 + f], s);
    Xb[(size_t)i * 256 + f] = f2bf(s);
}

// ------------------------- MFMA bf16 GEMM ----------------------------------
// C[M,256] = A[M,256] @ Bt^T, A/Bt/C bf16. 128x128 block tile, 4 waves,
// each wave 64x64 via 4x4 grid of 16x16x32 MFMAs, BK=32.
// LDS rows padded to 40 ushorts (80B): bank stride 20 -> worst 2-way (free).
__launch_bounds__(256)
__global__ void gemm_bf16_kernel(const ushort* __restrict__ A,
                                 const ushort* __restrict__ Bt,
                                 ushort* __restrict__ C, int M) {
    __shared__ __align__(16) ushort As[128][40];
    __shared__ __align__(16) ushort Bs[128][40];
    int tid = threadIdx.x;
    int lane = tid & 63;
    int w = tid >> 6;
    int wr = w >> 1, wc = w & 1;       // wave tile: rows wr*64, cols wc*64
    int lm = lane & 15, kq = lane >> 4;
    int row0 = blockIdx.y * 128;
    int col0 = blockIdx.x * 128;
    int sr = tid & 127;                // staging row
    int ss = tid >> 7;                 // staging k-half (16 bf16 = 32B)

    f32x4 acc[4][4] = {};

    for (int k0 = 0; k0 < 256; k0 += 32) {
        // stage A tile (rows guarded) and B tile
        {
            int grow = row0 + sr;
            uint4 p = make_uint4(0, 0, 0, 0), q = make_uint4(0, 0, 0, 0);
            if (grow < M) {
                const ushort* gp = A + (size_t)grow * 256 + k0 + ss * 16;
                p = *(const uint4*)gp;
                q = *(const uint4*)(gp + 8);
            }
            *(uint4*)&As[sr][ss * 16] = p;
            *(uint4*)&As[sr][ss * 16 + 8] = q;
            const ushort* gb = Bt + (size_t)(col0 + sr) * 256 + k0 + ss * 16;
            uint4 bp = *(const uint4*)gb;
            uint4 bq = *(const uint4*)(gb + 8);
            *(uint4*)&Bs[sr][ss * 16] = bp;
            *(uint4*)&Bs[sr][ss * 16 + 8] = bq;
        }
        __syncthreads();
        short8 af[4], bf[4];
        #pragma unroll
        for (int i = 0; i < 4; ++i)
            af[i] = *(const short8*)&As[wr * 64 + i * 16 + lm][kq * 8];
        #pragma unroll
        for (int j = 0; j < 4; ++j)
            bf[j] = *(const short8*)&Bs[wc * 64 + j * 16 + lm][kq * 8];
        #pragma unroll
        for (int i = 0; i < 4; ++i)
            #pragma unroll
            for (int j = 0; j < 4; ++j)
                acc[i][j] = __builtin_amdgcn_mfma_f32_16x16x32_bf16(
                    af[i], bf[j], acc[i][j], 0, 0, 0);
        __syncthreads();
    }

    // Epilogue: C/D layout col=lane&15, row=(lane>>4)*4+reg  [m89 verified]
    #pragma unroll
    for (int i = 0; i < 4; ++i) {
        #pragma unroll
        for (int j = 0; j < 4; ++j) {
            int col = col0 + wc * 64 + j * 16 + lm;
            #pragma unroll
            for (int r = 0; r < 4; ++r) {
                int grow = row0 + wr * 64 + i * 16 + kq * 4 + r;
                if (grow < M) C[(size_t)grow * 256 + col] = f2bf(acc[i][j][r]);
            }
        }
    }
}

// ---------------------- gather aggregation (bf16 X) ------------------------
__global__ void agg_kernel(const ushort* __restrict__ Xb,
                           float* __restrict__ Y,
                           const int* __restrict__ rowptr,
                           const int* __restrict__ srcp,
                           const float* __restrict__ normp,
                           const float* __restrict__ dinv,
                           const float* __restrict__ bias) {
    int node = (blockIdx.x << 2) + (threadIdx.x >> 6);
    if (node >= NN) return;
    int lane = threadIdx.x & 63;
    const uint2* X2 = (const uint2*)Xb;
    float di = dinv[node];
    float w0 = di * di;
    uint2 v = X2[(size_t)node * 64 + lane];
    float4 bb = ((const float4*)bias)[lane];
    float ax = fmaf(w0, bf_lo(v.x), bb.x);
    float ay = fmaf(w0, bf_hi(v.x), bb.y);
    float az = fmaf(w0, bf_lo(v.y), bb.z);
    float aw = fmaf(w0, bf_hi(v.y), bb.w);
    int j = rowptr[node], jend = rowptr[node + 1];
    for (; j < jend; ++j) {
        int s = srcp[j];
        float wt = normp[j];
        uint2 u = X2[(size_t)s * 64 + lane];
        ax = fmaf(wt, bf_lo(u.x), ax);
        ay = fmaf(wt, bf_hi(u.x), ay);
        az = fmaf(wt, bf_lo(u.y), az);
        aw = fmaf(wt, bf_hi(u.y), aw);
    }
    ((float4*)Y)[(size_t)node * 64 + lane] = make_float4(ax, ay, az, aw);
}

// ------------------------------- BatchNorm ---------------------------------
__global__ void bn_stats_kernel(const float* __restrict__ Y, float* __restrict__ stats) {
    int col = threadIdx.x;
    int r0 = blockIdx.x * 128;
    int rend = min(r0 + 128, NN);
    float s = 0.f, ss = 0.f;
    for (int r = r0; r < rend; ++r) {
        float v = Y[(size_t)r * 256 + col];
        s += v;
        ss = fmaf(v, v, ss);
    }
    unsafeAtomicAdd(&stats[col], s);
    unsafeAtomicAdd(&stats[256 + col], ss);
}

// BN apply + leakyReLU; fp32 in, bf16 out (next layer's GEMM input).
__global__ void bn_apply_kernel(const float* __restrict__ Y,
                                uint2* __restrict__ Act,
                                const float* __restrict__ stats,
                                const float* __restrict__ g,
                                const float* __restrict__ be) {
    int idx = blockIdx.x * 256 + threadIdx.x;  // over NN*64 float4s
    if (idx >= NN * 64) return;
    int c4 = idx & 63;
    float4 v = ((const float4*)Y)[idx];
    float4 s = ((const float4*)stats)[c4];
    float4 ss = ((const float4*)(stats + 256))[c4];
    float4 gg = ((const float4*)g)[c4];
    float4 bb = ((const float4*)be)[c4];
    const float invN = 1.0f / (float)NN;
    float m, var, sc, o;
    m = s.x * invN; var = fmaf(-m, m, ss.x * invN); sc = rsqrtf(var + 1e-5f) * gg.x;
    o = fmaf(v.x - m, sc, bb.x); v.x = (o >= 0.f) ? o : 0.01f * o;
    m = s.y * invN; var = fmaf(-m, m, ss.y * invN); sc = rsqrtf(var + 1e-5f) * gg.y;
    o = fmaf(v.y - m, sc, bb.y); v.y = (o >= 0.f) ? o : 0.01f * o;
    m = s.z * invN; var = fmaf(-m, m, ss.z * invN); sc = rsqrtf(var + 1e-5f) * gg.z;
    o = fmaf(v.z - m, sc, bb.z); v.z = (o >= 0.f) ? o : 0.01f * o;
    m = s.w * invN; var = fmaf(-m, m, ss.w * invN); sc = rsqrtf(var + 1e-5f) * gg.w;
    o = fmaf(v.w - m, sc, bb.w); v.w = (o >= 0.f) ? o : 0.01f * o;
    uint lo = (uint)f2bf(v.x) | ((uint)f2bf(v.y) << 16);
    uint hi = (uint)f2bf(v.z) | ((uint)f2bf(v.w) << 16);
    Act[idx] = make_uint2(lo, hi);
}

// ---------------------------------------------------------------------------

extern "C" void kernel_launch(void* const* d_in, const int* in_sizes, int n_in,
                              void* d_out, int out_size, void* d_ws, size_t ws_size,
                              hipStream_t stream) {
    const float* h   = (const float*)d_in[0];
    const int*   ei  = (const int*)d_in[1];
    const float* ew  = (const float*)d_in[2];
    const float* W1  = (const float*)d_in[3];
    const float* b1  = (const float*)d_in[4];
    const float* g1  = (const float*)d_in[5];
    const float* be1 = (const float*)d_in[6];
    const float* Wm  = (const float*)d_in[7];
    const float* bm  = (const float*)d_in[8];
    const float* gm  = (const float*)d_in[9];
    const float* bem = (const float*)d_in[10];
    const float* Wl  = (const float*)d_in[11];
    const float* bl  = (const float*)d_in[12];

    const int* src = ei;
    const int* dst = ei + NE;

    char* ws = (char*)d_ws;
    size_t off = 0;
    auto alloc = [&](size_t bytes) { size_t o = off; off = (off + bytes + 255) & ~(size_t)255; return o; };
    ushort* Xb    = (ushort*)(ws + alloc((size_t)NN * DD * 2));   // GEMM out, gather src (bf16)
    ushort* Act   = (ushort*)(ws + alloc((size_t)NN * DD * 2));   // BN out (bf16)
    float*  Y     = (float*) (ws + alloc((size_t)NN * DD * 4));   // agg out (fp32)
    ushort* Bt    = (ushort*)(ws + alloc((size_t)7 * DD * DD * 2)); // transposed weights
    float*  norm  = (float*) (ws + alloc((size_t)NE * 4));
    float*  dinv  = (float*) (ws + alloc((size_t)NN * 4));
    float*  stats = (float*) (ws + alloc(512 * 4));
    int*    rowptr= (int*)   (ws + alloc((size_t)(NN + 1) * 4));
    int*    cnt   = (int*)   (ws + alloc((size_t)NN * 4));
    int*    srcp  = (int*)   (ws + alloc((size_t)NE * 4));
    float*  normp = (float*) (ws + alloc((size_t)NE * 4));
    (void)ws_size;

    float* OUT = (float*)d_out;

    const int gN = (NN + 255) / 256;
    const int gE = (NE + 255) / 256;

    // --- gcn_norm + CSR build ---
    deg_init_kernel<<<gN, 256, 0, stream>>>(dinv);
    deg_scatter_kernel<<<gE, 256, 0, stream>>>(dst, ew, dinv);
    dinv_kernel<<<gN, 256, 0, stream>>>(dinv);
    hipMemsetAsync(cnt, 0, (size_t)NN * 4, stream);
    norm_cnt_kernel<<<gE, 256, 0, stream>>>(src, dst, ew, dinv, norm, cnt);
    scan_kernel<<<1, 1024, 0, stream>>>(cnt, rowptr, NN);
    hipMemsetAsync(cnt, 0, (size_t)NN * 4, stream);
    fill_kernel<<<gE, 256, 0, stream>>>(src, dst, norm, rowptr, cnt, srcp, normp);

    // --- weights -> bf16 transposed ---
    wcvt_kernel<<<(7 * 65536 + 255) / 256, 256, 0, stream>>>(Wm, Wl, Bt);

    // --- layer 0 GEMM ---
    gemm0_kernel<<<NN, 256, 0, stream>>>(h, W1, Xb);

    // --- 8 layers ---
    for (int l = 0; l < 8; ++l) {
        const float* b_l = (l == 0) ? b1 : (l <= 6 ? bm + (l - 1) * 256 : bl);
        if (l >= 1) {
            const ushort* Btl = Bt + (size_t)(l - 1) * DD * DD;
            dim3 grid(2, (NN + 127) / 128);
            gemm_bf16_kernel<<<grid, 256, 0, stream>>>(Act, Btl, Xb, NN);
        }
        float* Yl = (l == 7) ? OUT : Y;
        agg_kernel<<<(NN + 3) / 4, 256, 0, stream>>>(Xb, Yl, rowptr, srcp, normp, dinv, b_l);
        if (l < 7) {
            const float* g_l  = (l == 0) ? g1 : gm + (l - 1) * 256;
            const float* be_l = (l == 0) ? be1 : bem + (l - 1) * 256;
            hipMemsetAsync(stats, 0, 512 * 4, stream);
            bn_stats_kernel<<<(NN + 127) / 128, 256, 0, stream>>>(Y, stats);
            bn_apply_kernel<<<(NN * 64 + 255) / 256, 256, 0, stream>>>(
                Y, (uint2*)Act, stats, g_l, be_l);
        }
    }
}

// Round 3
// 1442.804 us; speedup vs baseline: 1.6304x; 1.1265x over previous
//
#include <hip/hip_runtime.h>
#include <hip/hip_bf16.h>

// ---------------------------------------------------------------------------
// EncoderGAE: 8-layer GCN encoder on MI355X.
// R3: agg 4x edge unroll (memory-level parallelism; R2 was latency-bound at
//     VGPR=12, BW fell to 2.6 TB/s) + bn_stats grid 391->1563 blocks.
// ---------------------------------------------------------------------------

#define NN 50000
#define NE 800000
#define DD 256

typedef __attribute__((ext_vector_type(8))) short short8;
typedef __attribute__((ext_vector_type(4))) float f32x4;

static __device__ __forceinline__ ushort f2bf(float f) {
    unsigned u = __float_as_uint(f);
    unsigned r = (u + 0x7fffu + ((u >> 16) & 1u)) >> 16;   // RNE
    return (ushort)r;
}
static __device__ __forceinline__ float bf_lo(unsigned x) {
    return __uint_as_float(x << 16);
}
static __device__ __forceinline__ float bf_hi(unsigned x) {
    return __uint_as_float(x & 0xffff0000u);
}

// ------------------------- gcn_norm + CSR build ----------------------------

__global__ void deg_init_kernel(float* deg) {
    int i = blockIdx.x * 256 + threadIdx.x;
    if (i < NN) deg[i] = 1.0f;  // self-loop weight 1
}

__global__ void deg_scatter_kernel(const int* __restrict__ dst,
                                   const float* __restrict__ ew,
                                   float* deg) {
    int e = blockIdx.x * 256 + threadIdx.x;
    if (e < NE) unsafeAtomicAdd(&deg[dst[e]], ew[e]);
}

__global__ void dinv_kernel(float* deg) {
    int i = blockIdx.x * 256 + threadIdx.x;
    if (i < NN) {
        float d = deg[i];
        deg[i] = (d > 0.0f) ? rsqrtf(fmaxf(d, 1e-30f)) : 0.0f;
    }
}

__global__ void norm_cnt_kernel(const int* __restrict__ src,
                                const int* __restrict__ dst,
                                const float* __restrict__ ew,
                                const float* __restrict__ dinv,
                                float* __restrict__ norm,
                                int* __restrict__ cnt) {
    int e = blockIdx.x * 256 + threadIdx.x;
    if (e < NE) {
        int s = src[e], d = dst[e];
        norm[e] = dinv[s] * ew[e] * dinv[d];
        atomicAdd(&cnt[d], 1);
    }
}

__global__ void scan_kernel(const int* __restrict__ cnt, int* __restrict__ rowptr, int n) {
    __shared__ int wsum[16];
    __shared__ int carry_s;
    int tid = threadIdx.x;
    int lane = tid & 63;
    int wid = tid >> 6;
    if (tid == 0) carry_s = 0;
    __syncthreads();
    for (int base = 0; base < n; base += 1024) {
        int i = base + tid;
        int v = (i < n) ? cnt[i] : 0;
        int x = v;
        #pragma unroll
        for (int o = 1; o < 64; o <<= 1) {
            int y = __shfl_up(x, o, 64);
            if (lane >= o) x += y;
        }
        if (lane == 63) wsum[wid] = x;
        __syncthreads();
        if (wid == 0) {
            int w = (lane < 16) ? wsum[lane] : 0;
            #pragma unroll
            for (int o = 1; o < 16; o <<= 1) {
                int y = __shfl_up(w, o, 64);
                if (lane >= o) w += y;
            }
            if (lane < 16) wsum[lane] = w;
        }
        __syncthreads();
        int wexcl = (wid > 0) ? wsum[wid - 1] : 0;
        int incl = x + wexcl;
        int c = carry_s;
        if (i < n) rowptr[i] = c + incl - v;
        __syncthreads();
        if (tid == 1023) carry_s = c + wsum[15];
        __syncthreads();
    }
    if (tid == 0) rowptr[n] = carry_s;
}

__global__ void fill_kernel(const int* __restrict__ src,
                            const int* __restrict__ dst,
                            const float* __restrict__ norm,
                            const int* __restrict__ rowptr,
                            int* __restrict__ cursor,
                            int* __restrict__ srcp,
                            float* __restrict__ normp) {
    int e = blockIdx.x * 256 + threadIdx.x;
    if (e < NE) {
        int d = dst[e];
        int p = rowptr[d] + atomicAdd(&cursor[d], 1);
        srcp[p] = src[e];
        normp[p] = norm[e];
    }
}

// ---------------------- weight transpose + bf16 cvt ------------------------
__global__ void wcvt_kernel(const float* __restrict__ Wm,
                            const float* __restrict__ Wl,
                            ushort* __restrict__ Bt) {
    int idx = blockIdx.x * 256 + threadIdx.x;
    if (idx >= 7 * 65536) return;
    int l = idx >> 16;
    int nk = idx & 65535;
    int n = nk >> 8, k = nk & 255;
    const float* W = (l < 6) ? (Wm + (size_t)l * 65536) : Wl;
    Bt[idx] = f2bf(W[k * 256 + n]);
}

// Layer-0: X[N,256] = h[N,6] @ W1[6,256], fp32 math, bf16 output.
__global__ void gemm0_kernel(const float* __restrict__ h,
                             const float* __restrict__ W1,
                             ushort* __restrict__ Xb) {
    __shared__ float hs[6];
    int i = blockIdx.x;
    int f = threadIdx.x;
    if (f < 6) hs[f] = h[i * 6 + f];
    __syncthreads();
    float s = 0.0f;
    #pragma unroll
    for (int k = 0; k < 6; ++k) s = fmaf(hs[k], W1[k * 256 + f], s);
    Xb[(size_t)i * 256 + f] = f2bf(s);
}

// ------------------------- MFMA bf16 GEMM ----------------------------------
__launch_bounds__(256)
__global__ void gemm_bf16_kernel(const ushort* __restrict__ A,
                                 const ushort* __restrict__ Bt,
                                 ushort* __restrict__ C, int M) {
    __shared__ __align__(16) ushort As[128][40];
    __shared__ __align__(16) ushort Bs[128][40];
    int tid = threadIdx.x;
    int lane = tid & 63;
    int w = tid >> 6;
    int wr = w >> 1, wc = w & 1;
    int lm = lane & 15, kq = lane >> 4;
    int row0 = blockIdx.y * 128;
    int col0 = blockIdx.x * 128;
    int sr = tid & 127;
    int ss = tid >> 7;

    f32x4 acc[4][4] = {};

    for (int k0 = 0; k0 < 256; k0 += 32) {
        {
            int grow = row0 + sr;
            uint4 p = make_uint4(0, 0, 0, 0), q = make_uint4(0, 0, 0, 0);
            if (grow < M) {
                const ushort* gp = A + (size_t)grow * 256 + k0 + ss * 16;
                p = *(const uint4*)gp;
                q = *(const uint4*)(gp + 8);
            }
            *(uint4*)&As[sr][ss * 16] = p;
            *(uint4*)&As[sr][ss * 16 + 8] = q;
            const ushort* gb = Bt + (size_t)(col0 + sr) * 256 + k0 + ss * 16;
            uint4 bp = *(const uint4*)gb;
            uint4 bq = *(const uint4*)(gb + 8);
            *(uint4*)&Bs[sr][ss * 16] = bp;
            *(uint4*)&Bs[sr][ss * 16 + 8] = bq;
        }
        __syncthreads();
        short8 af[4], bf[4];
        #pragma unroll
        for (int i = 0; i < 4; ++i)
            af[i] = *(const short8*)&As[wr * 64 + i * 16 + lm][kq * 8];
        #pragma unroll
        for (int j = 0; j < 4; ++j)
            bf[j] = *(const short8*)&Bs[wc * 64 + j * 16 + lm][kq * 8];
        #pragma unroll
        for (int i = 0; i < 4; ++i)
            #pragma unroll
            for (int j = 0; j < 4; ++j)
                acc[i][j] = __builtin_amdgcn_mfma_f32_16x16x32_bf16(
                    af[i], bf[j], acc[i][j], 0, 0, 0);
        __syncthreads();
    }

    #pragma unroll
    for (int i = 0; i < 4; ++i) {
        #pragma unroll
        for (int j = 0; j < 4; ++j) {
            int col = col0 + wc * 64 + j * 16 + lm;
            #pragma unroll
            for (int r = 0; r < 4; ++r) {
                int grow = row0 + wr * 64 + i * 16 + kq * 4 + r;
                if (grow < M) C[(size_t)grow * 256 + col] = f2bf(acc[i][j][r]);
            }
        }
    }
}

// ---------------------- gather aggregation (bf16 X) ------------------------
// One wave per dst node; 4x unrolled edge loop for memory-level parallelism.
__global__ void agg_kernel(const ushort* __restrict__ Xb,
                           float* __restrict__ Y,
                           const int* __restrict__ rowptr,
                           const int* __restrict__ srcp,
                           const float* __restrict__ normp,
                           const float* __restrict__ dinv,
                           const float* __restrict__ bias) {
    int node = (blockIdx.x << 2) + (threadIdx.x >> 6);
    if (node >= NN) return;
    int lane = threadIdx.x & 63;
    const uint2* X2 = (const uint2*)Xb;
    float di = dinv[node];
    float w0 = di * di;
    uint2 v = X2[(size_t)node * 64 + lane];
    float4 bb = ((const float4*)bias)[lane];
    float ax = fmaf(w0, bf_lo(v.x), bb.x);
    float ay = fmaf(w0, bf_hi(v.x), bb.y);
    float az = fmaf(w0, bf_lo(v.y), bb.z);
    float aw = fmaf(w0, bf_hi(v.y), bb.w);
    int j = rowptr[node], jend = rowptr[node + 1];
    int jstop = j + ((jend - j) & ~3);
    for (; j < jstop; j += 4) {
        int s0 = srcp[j + 0], s1 = srcp[j + 1], s2 = srcp[j + 2], s3 = srcp[j + 3];
        float t0 = normp[j + 0], t1 = normp[j + 1], t2 = normp[j + 2], t3 = normp[j + 3];
        uint2 u0 = X2[(size_t)s0 * 64 + lane];
        uint2 u1 = X2[(size_t)s1 * 64 + lane];
        uint2 u2 = X2[(size_t)s2 * 64 + lane];
        uint2 u3 = X2[(size_t)s3 * 64 + lane];
        ax = fmaf(t0, bf_lo(u0.x), ax); ay = fmaf(t0, bf_hi(u0.x), ay);
        az = fmaf(t0, bf_lo(u0.y), az); aw = fmaf(t0, bf_hi(u0.y), aw);
        ax = fmaf(t1, bf_lo(u1.x), ax); ay = fmaf(t1, bf_hi(u1.x), ay);
        az = fmaf(t1, bf_lo(u1.y), az); aw = fmaf(t1, bf_hi(u1.y), aw);
        ax = fmaf(t2, bf_lo(u2.x), ax); ay = fmaf(t2, bf_hi(u2.x), ay);
        az = fmaf(t2, bf_lo(u2.y), az); aw = fmaf(t2, bf_hi(u2.y), aw);
        ax = fmaf(t3, bf_lo(u3.x), ax); ay = fmaf(t3, bf_hi(u3.x), ay);
        az = fmaf(t3, bf_lo(u3.y), az); aw = fmaf(t3, bf_hi(u3.y), aw);
    }
    for (; j < jend; ++j) {
        int s = srcp[j];
        float wt = normp[j];
        uint2 u = X2[(size_t)s * 64 + lane];
        ax = fmaf(wt, bf_lo(u.x), ax);
        ay = fmaf(wt, bf_hi(u.x), ay);
        az = fmaf(wt, bf_lo(u.y), az);
        aw = fmaf(wt, bf_hi(u.y), aw);
    }
    ((float4*)Y)[(size_t)node * 64 + lane] = make_float4(ax, ay, az, aw);
}

// ------------------------------- BatchNorm ---------------------------------
// 32 rows/block -> 1563 blocks (~6/CU); R2's 128 rows/block was 1.5/CU.
__global__ void bn_stats_kernel(const float* __restrict__ Y, float* __restrict__ stats) {
    int col = threadIdx.x;
    int r0 = blockIdx.x * 32;
    int rend = min(r0 + 32, NN);
    float s = 0.f, ss = 0.f;
    #pragma unroll 4
    for (int r = r0; r < rend; ++r) {
        float v = Y[(size_t)r * 256 + col];
        s += v;
        ss = fmaf(v, v, ss);
    }
    unsafeAtomicAdd(&stats[col], s);
    unsafeAtomicAdd(&stats[256 + col], ss);
}

__global__ void bn_apply_kernel(const float* __restrict__ Y,
                                uint2* __restrict__ Act,
                                const float* __restrict__ stats,
                                const float* __restrict__ g,
                                const float* __restrict__ be) {
    int idx = blockIdx.x * 256 + threadIdx.x;
    if (idx >= NN * 64) return;
    int c4 = idx & 63;
    float4 v = ((const float4*)Y)[idx];
    float4 s = ((const float4*)stats)[c4];
    float4 ss = ((const float4*)(stats + 256))[c4];
    float4 gg = ((const float4*)g)[c4];
    float4 bb = ((const float4*)be)[c4];
    const float invN = 1.0f / (float)NN;
    float m, var, sc, o;
    m = s.x * invN; var = fmaf(-m, m, ss.x * invN); sc = rsqrtf(var + 1e-5f) * gg.x;
    o = fmaf(v.x - m, sc, bb.x); v.x = (o >= 0.f) ? o : 0.01f * o;
    m = s.y * invN; var = fmaf(-m, m, ss.y * invN); sc = rsqrtf(var + 1e-5f) * gg.y;
    o = fmaf(v.y - m, sc, bb.y); v.y = (o >= 0.f) ? o : 0.01f * o;
    m = s.z * invN; var = fmaf(-m, m, ss.z * invN); sc = rsqrtf(var + 1e-5f) * gg.z;
    o = fmaf(v.z - m, sc, bb.z); v.z = (o >= 0.f) ? o : 0.01f * o;
    m = s.w * invN; var = fmaf(-m, m, ss.w * invN); sc = rsqrtf(var + 1e-5f) * gg.w;
    o = fmaf(v.w - m, sc, bb.w); v.w = (o >= 0.f) ? o : 0.01f * o;
    uint lo = (uint)f2bf(v.x) | ((uint)f2bf(v.y) << 16);
    uint hi = (uint)f2bf(v.z) | ((uint)f2bf(v.w) << 16);
    Act[idx] = make_uint2(lo, hi);
}

// ---------------------------------------------------------------------------

extern "C" void kernel_launch(void* const* d_in, const int* in_sizes, int n_in,
                              void* d_out, int out_size, void* d_ws, size_t ws_size,
                              hipStream_t stream) {
    const float* h   = (const float*)d_in[0];
    const int*   ei  = (const int*)d_in[1];
    const float* ew  = (const float*)d_in[2];
    const float* W1  = (const float*)d_in[3];
    const float* b1  = (const float*)d_in[4];
    const float* g1  = (const float*)d_in[5];
    const float* be1 = (const float*)d_in[6];
    const float* Wm  = (const float*)d_in[7];
    const float* bm  = (const float*)d_in[8];
    const float* gm  = (const float*)d_in[9];
    const float* bem = (const float*)d_in[10];
    const float* Wl  = (const float*)d_in[11];
    const float* bl  = (const float*)d_in[12];

    const int* src = ei;
    const int* dst = ei + NE;

    char* ws = (char*)d_ws;
    size_t off = 0;
    auto alloc = [&](size_t bytes) { size_t o = off; off = (off + bytes + 255) & ~(size_t)255; return o; };
    ushort* Xb    = (ushort*)(ws + alloc((size_t)NN * DD * 2));
    ushort* Act   = (ushort*)(ws + alloc((size_t)NN * DD * 2));
    float*  Y     = (float*) (ws + alloc((size_t)NN * DD * 4));
    ushort* Bt    = (ushort*)(ws + alloc((size_t)7 * DD * DD * 2));
    float*  norm  = (float*) (ws + alloc((size_t)NE * 4));
    float*  dinv  = (float*) (ws + alloc((size_t)NN * 4));
    float*  stats = (float*) (ws + alloc(512 * 4));
    int*    rowptr= (int*)   (ws + alloc((size_t)(NN + 1) * 4));
    int*    cnt   = (int*)   (ws + alloc((size_t)NN * 4));
    int*    srcp  = (int*)   (ws + alloc((size_t)NE * 4));
    float*  normp = (float*) (ws + alloc((size_t)NE * 4));
    (void)ws_size;

    float* OUT = (float*)d_out;

    const int gN = (NN + 255) / 256;
    const int gE = (NE + 255) / 256;

    deg_init_kernel<<<gN, 256, 0, stream>>>(dinv);
    deg_scatter_kernel<<<gE, 256, 0, stream>>>(dst, ew, dinv);
    dinv_kernel<<<gN, 256, 0, stream>>>(dinv);
    hipMemsetAsync(cnt, 0, (size_t)NN * 4, stream);
    norm_cnt_kernel<<<gE, 256, 0, stream>>>(src, dst, ew, dinv, norm, cnt);
    scan_kernel<<<1, 1024, 0, stream>>>(cnt, rowptr, NN);
    hipMemsetAsync(cnt, 0, (size_t)NN * 4, stream);
    fill_kernel<<<gE, 256, 0, stream>>>(src, dst, norm, rowptr, cnt, srcp, normp);

    wcvt_kernel<<<(7 * 65536 + 255) / 256, 256, 0, stream>>>(Wm, Wl, Bt);

    gemm0_kernel<<<NN, 256, 0, stream>>>(h, W1, Xb);

    for (int l = 0; l < 8; ++l) {
        const float* b_l = (l == 0) ? b1 : (l <= 6 ? bm + (l - 1) * 256 : bl);
        if (l >= 1) {
            const ushort* Btl = Bt + (size_t)(l - 1) * DD * DD;
            dim3 grid(2, (NN + 127) / 128);
            gemm_bf16_kernel<<<grid, 256, 0, stream>>>(Act, Btl, Xb, NN);
        }
        float* Yl = (l == 7) ? OUT : Y;
        agg_kernel<<<(NN + 3) / 4, 256, 0, stream>>>(Xb, Yl, rowptr, srcp, normp, dinv, b_l);
        if (l < 7) {
            const float* g_l  = (l == 0) ? g1 : gm + (l - 1) * 256;
            const float* be_l = (l == 0) ? be1 : bem + (l - 1) * 256;
            hipMemsetAsync(stats, 0, 512 * 4, stream);
            bn_stats_kernel<<<(NN + 31) / 32, 256, 0, stream>>>(Y, stats);
            bn_apply_kernel<<<(NN * 64 + 255) / 256, 256, 0, stream>>>(
                Y, (uint2*)Act, stats, g_l, be_l);
        }
    }
}